// Round 2
// baseline (6792.657 us; speedup 1.0000x reference)
//
#include <hip/hip_runtime.h>

#define N_TOK  65536
#define N_CODE 8192
#define DIM    256
#define TM     64
#define TN     128
#define BK     32

// ---------- kernel 1: row sum-of-squares (one wave per row) ----------
__global__ __launch_bounds__(256) void rowsq_kernel(const float* __restrict__ src,
                                                    float* __restrict__ dst, int nrows) {
    int row  = blockIdx.x * 4 + (threadIdx.x >> 6);
    int lane = threadIdx.x & 63;
    if (row >= nrows) return;
    float4 v = ((const float4*)(src + (size_t)row * DIM))[lane];
    float s = v.x * v.x + v.y * v.y + v.z * v.z + v.w * v.w;
#pragma unroll
    for (int off = 32; off; off >>= 1) s += __shfl_down(s, off, 64);
    if (lane == 0) dst[row] = s;
}

// ---------- kernel 2: fused GEMM + argmin ----------
// block: 256 threads = 16 (code dim, tx) x 16 (token dim, ty)
// tile: TM=64 tokens x TN=128 codes; thread tile 4 tokens x 8 codes
// X tile resident in LDS [k][token] (swizzled); W staged in BK-chunks [k][code] (swizzled)
__global__ __launch_bounds__(256) void argmin_kernel(
    const float* __restrict__ X, const float* __restrict__ W,
    const float* __restrict__ sxq, const float* __restrict__ esq,
    int* __restrict__ out_idx) {

    __shared__ float sXs[DIM * TM];   // 65536 B
    __shared__ float sWs[BK * TN];    // 16384 B

    int tid = threadIdx.x;
    int tx = tid & 15;   // code dim
    int ty = tid >> 4;   // token dim
    int tok0 = blockIdx.x * TM;

    // ---- stage X tile: 64 rows x 256 floats, transposed + swizzled ----
    // element (k, tok) stored at sXs[k*TM + (tok ^ (((k>>2)&15)<<2))]
#pragma unroll
    for (int it = 0; it < 16; ++it) {
        int flat = it * 256 + tid;   // float4 id, 0..4095
        int row  = flat >> 6;        // token-local 0..63
        int c4   = flat & 63;        // float4 col in dim
        float4 v = ((const float4*)(X + (size_t)(tok0 + row) * DIM))[c4];
        int cs = row ^ ((c4 & 15) << 2);
        sXs[(4 * c4 + 0) * TM + cs] = v.x;
        sXs[(4 * c4 + 1) * TM + cs] = v.y;
        sXs[(4 * c4 + 2) * TM + cs] = v.z;
        sXs[(4 * c4 + 3) * TM + cs] = v.w;
    }

    float sx[4];
#pragma unroll
    for (int i = 0; i < 4; ++i) sx[i] = sxq[tok0 + ty * 4 + i];

    float bestd[4];
    int   besti[4];
#pragma unroll
    for (int i = 0; i < 4; ++i) { bestd[i] = 3.4e38f; besti[i] = 0; }

    for (int tile = 0; tile < N_CODE / TN; ++tile) {
        int code0 = tile * TN;
        float acc[4][8];
#pragma unroll
        for (int i = 0; i < 4; ++i)
#pragma unroll
            for (int j = 0; j < 8; ++j) acc[i][j] = 0.f;

        for (int ch = 0; ch < DIM / BK; ++ch) {
            __syncthreads();   // previous chunk's readers done before overwrite
            // stage W chunk: 128 codes x 32 k = 1024 float4, 4 per thread
#pragma unroll
            for (int it = 0; it < 4; ++it) {
                int flat = it * 256 + tid;   // 0..1023
                int cl = flat >> 3;          // code local 0..127
                int kq = flat & 7;           // k-float4 within chunk 0..7
                float4 w = ((const float4*)(W + (size_t)(code0 + cl) * DIM + ch * BK))[kq];
                int cc = cl ^ (kq << 2);     // swizzled code column
                sWs[(4 * kq + 0) * TN + cc] = w.x;
                sWs[(4 * kq + 1) * TN + cc] = w.y;
                sWs[(4 * kq + 2) * TN + cc] = w.z;
                sWs[(4 * kq + 3) * TN + cc] = w.w;
            }
            __syncthreads();

#pragma unroll
            for (int kk = 0; kk < BK; ++kk) {
                int k  = ch * BK + kk;
                int sX = (k >> 2) & 15;
                int kq = kk >> 2;
                float4 xv = *(const float4*)(sXs + k * TM + 4 * (ty ^ sX));
                float4 w0 = *(const float4*)(sWs + kk * TN + 4 * ((2 * tx) ^ kq));
                float4 w1 = *(const float4*)(sWs + kk * TN + 4 * ((2 * tx + 1) ^ kq));
                float xr[4] = {xv.x, xv.y, xv.z, xv.w};
                float wr[8] = {w0.x, w0.y, w0.z, w0.w, w1.x, w1.y, w1.z, w1.w};
#pragma unroll
                for (int i = 0; i < 4; ++i)
#pragma unroll
                    for (int j = 0; j < 8; ++j)
                        acc[i][j] += xr[i] * wr[j];
            }
        }

        // argmin update for this code tile — replicate ref f32 rounding:
        // d = fl( fl(sx + se) - 2*dot )   (2*dot exact in fp)
        // within-thread visit order is strictly ascending code index, so
        // strict < keeps the lowest tied index.
        float4 e0 = ((const float4*)(esq + code0 + tx * 8))[0];
        float4 e1 = ((const float4*)(esq + code0 + tx * 8))[1];
        float er[8] = {e0.x, e0.y, e0.z, e0.w, e1.x, e1.y, e1.z, e1.w};
#pragma unroll
        for (int i = 0; i < 4; ++i) {
#pragma unroll
            for (int j = 0; j < 8; ++j) {
                float t1 = sx[i] + er[j];
                float d  = t1 - 2.0f * acc[i][j];
                if (d < bestd[i]) { bestd[i] = d; besti[i] = code0 + tx * 8 + j; }
            }
        }
    }

    // ---- cross-thread (tx) reduction, aliasing sXs ----
    // tx order is NOT code order (tx owns a strided subsequence of codes),
    // so ties MUST be broken by lexicographic (distance, index) — np.argmin
    // returns the globally lowest index among equal minima.
    __syncthreads();
    float* redD = sXs;                     // 64*16 floats
    int*   redI = (int*)(sXs + TM * 16);   // 64*16 ints
#pragma unroll
    for (int i = 0; i < 4; ++i) {
        redD[(ty * 4 + i) * 16 + tx] = bestd[i];
        redI[(ty * 4 + i) * 16 + tx] = besti[i];
    }
    __syncthreads();
    if (tid < TM) {
        float bd = 3.4e38f; int bi = 0x7fffffff;
        for (int t = 0; t < 16; ++t) {
            float d = redD[tid * 16 + t];
            int  ii = redI[tid * 16 + t];
            if (d < bd || (d == bd && ii < bi)) { bd = d; bi = ii; }
        }
        out_idx[tok0 + tid] = bi;
    }
}

// ---------- kernel 3: gather + straight-through output + loss partials ----------
__global__ __launch_bounds__(256) void finalize_kernel(
    const float* __restrict__ X, const float* __restrict__ W,
    const int* __restrict__ idx, float* __restrict__ outQ,
    float* __restrict__ outI, double* __restrict__ accum) {
    __shared__ double wsum[4];
    int wid  = threadIdx.x >> 6;
    int lane = threadIdx.x & 63;
    int token = blockIdx.x * 4 + wid;
    int id = idx[token];
    float4 x = ((const float4*)(X + (size_t)token * DIM))[lane];
    float4 q = ((const float4*)(W + (size_t)id * DIM))[lane];
    float4 o;
    o.x = x.x + (q.x - x.x);   // replicate ref rounding (no reassociation w/o fast-math)
    o.y = x.y + (q.y - x.y);
    o.z = x.z + (q.z - x.z);
    o.w = x.w + (q.w - x.w);
    ((float4*)(outQ + (size_t)token * DIM))[lane] = o;
    float dx = x.x - q.x, dy = x.y - q.y, dz = x.z - q.z, dw = x.w - q.w;
    float s = dx * dx + dy * dy + dz * dz + dw * dw;
#pragma unroll
    for (int off = 32; off; off >>= 1) s += __shfl_down(s, off, 64);
    if (lane == 0) {
        outI[token] = (float)id;
        wsum[wid] = (double)s;
    }
    __syncthreads();
    if (threadIdx.x == 0) {
        double t = wsum[0] + wsum[1] + wsum[2] + wsum[3];
        atomicAdd(accum, t);
    }
}

// ---------- kernel 4: scalars ----------
__global__ void scalars_kernel(const double* __restrict__ accum, float* __restrict__ out) {
    double mse = *accum / (double)((size_t)N_TOK * DIM);
    float c = (float)mse;
    out[0] = c + 0.25f * c;  // vq_loss = codebook + 0.25*commit
    out[1] = c;              // codebook_loss
    out[2] = c;              // commit_loss
}

extern "C" void kernel_launch(void* const* d_in, const int* in_sizes, int n_in,
                              void* d_out, int out_size, void* d_ws, size_t ws_size,
                              hipStream_t stream) {
    const float* X = (const float*)d_in[0];   // (65536, 256)
    const float* W = (const float*)d_in[1];   // (8192, 256)

    float* outQ = (float*)d_out;                       // 65536*256
    float* outI = outQ + (size_t)N_TOK * DIM;          // 65536 (indices as float)
    float* outS = outI + N_TOK;                        // 3 scalars

    char* ws = (char*)d_ws;
    double* accum = (double*)ws;                       // 8 B
    float* esq = (float*)(ws + 64);                    // 8192 f
    float* sxq = (float*)(ws + 64 + 32768);            // 65536 f
    int*   idx = (int*)(ws + 64 + 32768 + 262144);     // 65536 i32

    hipMemsetAsync(accum, 0, sizeof(double), stream);
    rowsq_kernel<<<N_CODE / 4, 256, 0, stream>>>(W, esq, N_CODE);
    rowsq_kernel<<<N_TOK / 4, 256, 0, stream>>>(X, sxq, N_TOK);
    argmin_kernel<<<N_TOK / TM, 256, 0, stream>>>(X, W, sxq, esq, idx);
    finalize_kernel<<<N_TOK / 4, 256, 0, stream>>>(X, W, idx, outQ, outI, accum);
    scalars_kernel<<<1, 1, 0, stream>>>(accum, outS);
}

// Round 3
// 1659.008 us; speedup vs baseline: 4.0944x; 4.0944x over previous
//
#include <hip/hip_runtime.h>

#define N_TOK  65536
#define N_CODE 8192
#define DIM    256
#define TM     128        // tokens per block (X resident in LDS)
#define TN     128        // codes per tile
#define BK     32         // k per W chunk

typedef _Float16 f16;
typedef _Float16 f16x8 __attribute__((ext_vector_type(8)));
typedef float    f32x4 __attribute__((ext_vector_type(4)));

// ---------- kernel 1: row sum-of-squares (one wave per row) ----------
__global__ __launch_bounds__(256) void rowsq_kernel(const float* __restrict__ src,
                                                    float* __restrict__ dst, int nrows) {
    int row  = blockIdx.x * 4 + (threadIdx.x >> 6);
    int lane = threadIdx.x & 63;
    if (row >= nrows) return;
    float4 v = ((const float4*)(src + (size_t)row * DIM))[lane];
    float s = v.x * v.x + v.y * v.y + v.z * v.z + v.w * v.w;
#pragma unroll
    for (int off = 32; off; off >>= 1) s += __shfl_down(s, off, 64);
    if (lane == 0) dst[row] = s;
}

// ---------- kernel 2: split W into 2 fp16 limbs ----------
// w_s = w*2^14 (range ±2, normal fp16); w1 = f16(w_s); w2s = f16((w_s-w1)*2^11)
// Both limbs subnormal-free; products with them are exact in fp32.
__global__ __launch_bounds__(256) void splitw_kernel(const float* __restrict__ W,
                                                     f16* __restrict__ W1,
                                                     f16* __restrict__ W2) {
    int f = blockIdx.x * 256 + threadIdx.x;          // float4 id, 524288 total
    float4 v = ((const float4*)W)[f];
    union { f16 h[4]; uint2 u; } p1, p2;
    float e[4] = {v.x, v.y, v.z, v.w};
#pragma unroll
    for (int i = 0; i < 4; ++i) {
        float ws = e[i] * 16384.0f;                  // exact (pow2)
        f16 w1 = (f16)ws;                            // RNE
        float r = (ws - (float)w1) * 2048.0f;        // exact (Sterbenz + pow2)
        p1.h[i] = w1; p2.h[i] = (f16)r;
    }
    ((uint2*)W1)[f] = p1.u;
    ((uint2*)W2)[f] = p2.u;
}

// ---------- kernel 3: fused MFMA GEMM + argmin ----------
// 256 thr = 4 waves (wm = wave>>1 token-half, wn = wave&1 code-half), wave tile 64x64.
// LDS: X1 [0,64K), X2s [64K,128K)  (resident, split in-kernel)
//      Wbuf [128K,144K): limb0 8KB, limb1 8KB  (single buffer, reg-prefetched)
// 16-B segments swizzled so 8 consecutive lanes hit 8 distinct bank-quads.
__global__ __launch_bounds__(256, 1) void argmin_mfma_kernel(
    const float* __restrict__ X, const f16* __restrict__ W1, const f16* __restrict__ W2,
    const float* __restrict__ sxq, const float* __restrict__ esq,
    int* __restrict__ out_idx) {

    __shared__ char lds[147456];

    const int tid  = threadIdx.x;
    const int lane = tid & 63;
    const int wv   = tid >> 6;        // 0..3
    const int wm   = wv >> 1;         // token half (0..1)
    const int wn   = wv & 1;          // code half (0..1)
    const int l15  = lane & 15;
    const int q    = lane >> 4;       // 0..3 (k-octet selector)
    const int t7   = l15 & 7;
    const int tok0 = blockIdx.x * TM;

    // ---- stage X resident: read fp32, split into 2 fp16 limbs, write LDS ----
    // seg s (=k/8) of row tok stored at tok*512 + ((s^(tok&7))*16); b64 halves.
#pragma unroll
    for (int it = 0; it < 32; ++it) {
        int flat = it * 256 + tid;                   // float4 id 0..8191
        int tok  = flat >> 6;                        // 0..127
        int c4   = flat & 63;
        float4 v = ((const float4*)(X + (size_t)(tok0 + tok) * DIM))[c4];
        int s = c4 >> 1;
        int dst = tok * 512 + ((s ^ (tok & 7)) * 16) + (c4 & 1) * 8;
        union { f16 h[4]; uint2 u; } p1, p2;
        float e[4] = {v.x, v.y, v.z, v.w};
#pragma unroll
        for (int i = 0; i < 4; ++i) {
            f16 x1 = (f16)e[i];                      // RNE
            float r = (e[i] - (float)x1) * 2048.0f;  // exact
            p1.h[i] = x1; p2.h[i] = (f16)r;
        }
        *(uint2*)(lds + dst)         = p1.u;
        *(uint2*)(lds + 65536 + dst) = p2.u;
    }

    // sx for this lane's 16 token-rows (fixed for whole kernel)
    float sx_r[16];
#pragma unroll
    for (int mt = 0; mt < 4; ++mt)
#pragma unroll
        for (int r = 0; r < 4; ++r)
            sx_r[mt * 4 + r] = sxq[tok0 + wm * 64 + mt * 16 + q * 4 + r];

    float bestd[16];
    int   besti[16];
#pragma unroll
    for (int i = 0; i < 16; ++i) { bestd[i] = 3.4e38f; besti[i] = 0; }

    // W-frag base (constant across chunks/tiles): code = wn*64 + nt*16 + l15
    // (code>>1)&3 == (l15>>1)&3 since nt*16, wn*64 only touch bits>=4.
    const int wfrag = (wn * 64 + l15) * 64 + ((q ^ ((l15 >> 1) & 3)) * 16);
    const int xbase = (wm * 64 + l15) * 512;
    char* const wbuf = lds + 131072;

    uint4 hold[4];

    for (int ct = 0; ct < N_CODE / TN; ++ct) {
        const int code0 = ct * TN;

        // prefetch chunk 0 of this tile
#pragma unroll
        for (int it = 0; it < 4; ++it) {
            int e = it * 256 + tid;                  // 0..1023
            int limb = it >> 1;                      // e>>9
            int g = e & 511, code = g >> 2, qq = g & 3;
            const f16* src = (limb ? W2 : W1) + (size_t)(code0 + code) * DIM + qq * 8;
            hold[it] = *(const uint4*)src;
        }

        float se[4];
#pragma unroll
        for (int nt = 0; nt < 4; ++nt)
            se[nt] = esq[code0 + wn * 64 + nt * 16 + l15];

        f32x4 mainacc[16];
#pragma unroll
        for (int t = 0; t < 16; ++t) mainacc[t] = (f32x4){0.f, 0.f, 0.f, 0.f};

        for (int ch = 0; ch < 8; ++ch) {
            __syncthreads();                         // all waves done reading Wbuf
            // write held chunk
#pragma unroll
            for (int it = 0; it < 4; ++it) {
                int e = it * 256 + tid;
                int limb = it >> 1;
                int g = e & 511, code = g >> 2, qq = g & 3;
                int dst = limb * 8192 + code * 64 + ((qq ^ ((code >> 1) & 3)) * 16);
                *(uint4*)(wbuf + dst) = hold[it];
            }
            // prefetch next chunk into regs (overlaps barrier+compute)
            if (ch < 7) {
                int k0n = (ch + 1) * BK;
#pragma unroll
                for (int it = 0; it < 4; ++it) {
                    int e = it * 256 + tid;
                    int limb = it >> 1;
                    int g = e & 511, code = g >> 2, qq = g & 3;
                    const f16* src = (limb ? W2 : W1) + (size_t)(code0 + code) * DIM + k0n + qq * 8;
                    hold[it] = *(const uint4*)src;
                }
            }
            __syncthreads();                         // chunk visible

            // fragment reads
            int xo = xbase + (((ch * 4 + q) ^ t7) * 16);
            f16x8 a1[4], a2[4], b1[4], b2[4];
#pragma unroll
            for (int mt = 0; mt < 4; ++mt) {
                a1[mt] = *(const f16x8*)(lds + xo + mt * 8192);
                a2[mt] = *(const f16x8*)(lds + 65536 + xo + mt * 8192);
            }
#pragma unroll
            for (int nt = 0; nt < 4; ++nt) {
                b1[nt] = *(const f16x8*)(wbuf + wfrag + nt * 1024);
                b2[nt] = *(const f16x8*)(wbuf + 8192 + wfrag + nt * 1024);
            }
            // 3 products: main += x1w1 ; tmp = x1w2 + x2w1 ; main += tmp*2^-11
#pragma unroll
            for (int mt = 0; mt < 4; ++mt)
#pragma unroll
                for (int nt = 0; nt < 4; ++nt) {
                    int t = mt * 4 + nt;
                    f32x4 tmp = (f32x4){0.f, 0.f, 0.f, 0.f};
                    tmp = __builtin_amdgcn_mfma_f32_16x16x32_f16(a1[mt], b2[nt], tmp, 0, 0, 0);
                    tmp = __builtin_amdgcn_mfma_f32_16x16x32_f16(a2[mt], b1[nt], tmp, 0, 0, 0);
                    mainacc[t] = __builtin_amdgcn_mfma_f32_16x16x32_f16(a1[mt], b1[nt], mainacc[t], 0, 0, 0);
#pragma unroll
                    for (int r = 0; r < 4; ++r)
                        mainacc[t][r] = fmaf(tmp[r], 4.8828125e-4f, mainacc[t][r]);  // *2^-11
                }
        }

        // epilogue: d = fl(fl(sx+se) - 2*dot), dot*2^14 = mainacc -> 2*dot = mainacc*2^-13
        // within-lane visit order is ascending code (nt, ct ascending): strict < keeps leftmost.
#pragma unroll
        for (int mt = 0; mt < 4; ++mt)
#pragma unroll
            for (int nt = 0; nt < 4; ++nt)
#pragma unroll
                for (int r = 0; r < 4; ++r) {
                    float t1 = sx_r[mt * 4 + r] + se[nt];
                    float d  = fmaf(-1.220703125e-4f, mainacc[mt * 4 + nt][r], t1);
                    int i = mt * 4 + r;
                    if (d < bestd[i]) {
                        bestd[i] = d;
                        besti[i] = code0 + wn * 64 + nt * 16 + l15;
                    }
                }
    }

    // ---- cross-lane reduction (alias X region; X no longer needed) ----
    __syncthreads();
    float* redD = (float*)lds;                       // 128 tok x 32 cand
    int*   redI = (int*)(lds + 16384);
#pragma unroll
    for (int mt = 0; mt < 4; ++mt)
#pragma unroll
        for (int r = 0; r < 4; ++r) {
            int tokl = wm * 64 + mt * 16 + q * 4 + r;
            int cand = wn * 16 + l15;
            redD[tokl * 32 + cand] = bestd[mt * 4 + r];
            redI[tokl * 32 + cand] = besti[mt * 4 + r];
        }
    __syncthreads();
    if (tid < TM) {
        float bd = 3.4e38f; int bi = 0x7fffffff;
        for (int c = 0; c < 32; ++c) {
            float d = redD[tid * 32 + c];
            int  ii = redI[tid * 32 + c];
            if (d < bd || (d == bd && ii < bi)) { bd = d; bi = ii; }
        }
        out_idx[tok0 + tid] = bi;
    }
}

// ---------- kernel 4: gather + straight-through output + loss partials ----------
__global__ __launch_bounds__(256) void finalize_kernel(
    const float* __restrict__ X, const float* __restrict__ W,
    const int* __restrict__ idx, float* __restrict__ outQ,
    float* __restrict__ outI, double* __restrict__ accum) {
    __shared__ double wsum[4];
    int wid  = threadIdx.x >> 6;
    int lane = threadIdx.x & 63;
    int token = blockIdx.x * 4 + wid;
    int id = idx[token];
    float4 x = ((const float4*)(X + (size_t)token * DIM))[lane];
    float4 qv = ((const float4*)(W + (size_t)id * DIM))[lane];
    float4 o;
    o.x = x.x + (qv.x - x.x);
    o.y = x.y + (qv.y - x.y);
    o.z = x.z + (qv.z - x.z);
    o.w = x.w + (qv.w - x.w);
    ((float4*)(outQ + (size_t)token * DIM))[lane] = o;
    float dx = x.x - qv.x, dy = x.y - qv.y, dz = x.z - qv.z, dw = x.w - qv.w;
    float s = dx * dx + dy * dy + dz * dz + dw * dw;
#pragma unroll
    for (int off = 32; off; off >>= 1) s += __shfl_down(s, off, 64);
    if (lane == 0) {
        outI[token] = (float)id;
        wsum[wid] = (double)s;
    }
    __syncthreads();
    if (threadIdx.x == 0) {
        double t = wsum[0] + wsum[1] + wsum[2] + wsum[3];
        atomicAdd(accum, t);
    }
}

// ---------- kernel 5: scalars ----------
__global__ void scalars_kernel(const double* __restrict__ accum, float* __restrict__ out) {
    double mse = *accum / (double)((size_t)N_TOK * DIM);
    float c = (float)mse;
    out[0] = c + 0.25f * c;
    out[1] = c;
    out[2] = c;
}

extern "C" void kernel_launch(void* const* d_in, const int* in_sizes, int n_in,
                              void* d_out, int out_size, void* d_ws, size_t ws_size,
                              hipStream_t stream) {
    const float* X = (const float*)d_in[0];   // (65536, 256)
    const float* W = (const float*)d_in[1];   // (8192, 256)

    float* outQ = (float*)d_out;
    float* outI = outQ + (size_t)N_TOK * DIM;
    float* outS = outI + N_TOK;

    char* ws = (char*)d_ws;
    double* accum = (double*)ws;                         // @0
    float* esq = (float*)(ws + 64);                      // 32 KB
    float* sxq = (float*)(ws + 64 + 32768);              // 256 KB
    int*   idx = (int*)(ws + 64 + 32768 + 262144);       // 256 KB
    f16*   W1  = (f16*)(ws + (1 << 20));                 // 4 MB
    f16*   W2  = (f16*)(ws + (1 << 20) + 4194304);       // 4 MB

    hipMemsetAsync(accum, 0, sizeof(double), stream);
    splitw_kernel<<<N_CODE * DIM / 4 / 256, 256, 0, stream>>>(W, W1, W2);
    rowsq_kernel<<<N_CODE / 4, 256, 0, stream>>>(W, esq, N_CODE);
    rowsq_kernel<<<N_TOK / 4, 256, 0, stream>>>(X, sxq, N_TOK);
    argmin_mfma_kernel<<<N_TOK / TM, 256, 0, stream>>>(X, W1, W2, sxq, esq, idx);
    finalize_kernel<<<N_TOK / 4, 256, 0, stream>>>(X, W, idx, outQ, outI, accum);
    scalars_kernel<<<1, 1, 0, stream>>>(accum, outS);
}

// Round 4
// 930.179 us; speedup vs baseline: 7.3025x; 1.7835x over previous
//
#include <hip/hip_runtime.h>

#define N_TOK  65536
#define N_CODE 8192
#define DIM    256

typedef _Float16 f16;
typedef _Float16 f16x8 __attribute__((ext_vector_type(8)));
typedef float    f32x4 __attribute__((ext_vector_type(4)));

// ---------- kernel 1: row sum-of-squares (one wave per row) ----------
__global__ __launch_bounds__(256) void rowsq_kernel(const float* __restrict__ src,
                                                    float* __restrict__ dst, int nrows) {
    int row  = blockIdx.x * 4 + (threadIdx.x >> 6);
    int lane = threadIdx.x & 63;
    if (row >= nrows) return;
    float4 v = ((const float4*)(src + (size_t)row * DIM))[lane];
    float s = v.x * v.x + v.y * v.y + v.z * v.z + v.w * v.w;
#pragma unroll
    for (int off = 32; off; off >>= 1) s += __shfl_down(s, off, 64);
    if (lane == 0) dst[row] = s;
}

// ---------- kernel 2: split W into 2 fp16 limbs (pre-scaled, subnormal-free) ----------
__global__ __launch_bounds__(256) void splitw_kernel(const float* __restrict__ W,
                                                     f16* __restrict__ W1,
                                                     f16* __restrict__ W2) {
    int f = blockIdx.x * 256 + threadIdx.x;          // float4 id
    float4 v = ((const float4*)W)[f];
    union { f16 h[4]; uint2 u; } p1, p2;
    float e[4] = {v.x, v.y, v.z, v.w};
#pragma unroll
    for (int i = 0; i < 4; ++i) {
        float ws = e[i] * 16384.0f;                  // exact (pow2)
        f16 w1 = (f16)ws;                            // RNE
        float r = (ws - (float)w1) * 2048.0f;        // exact
        p1.h[i] = w1; p2.h[i] = (f16)r;
    }
    ((uint2*)W1)[f] = p1.u;
    ((uint2*)W2)[f] = p2.u;
}

// ---------- kernel 3: fused MFMA GEMM + argmin, v2 ----------
// 256 blocks x 512 thr (8 waves, 2/SIMD). Wave owns 32 tokens; A-frags (both
// limbs, full K=256) persistent in 128 VGPRs. B (32-code stripes) streamed
// through a 2x32KB LDS double-buffer via global_load_lds(16) with XOR-permuted
// per-lane global addresses (LDS wave-linear layout == conflict-free frag layout).
// 3 persistent accumulators (main, crossA, crossB) folded once per code-tile.
__global__ __launch_bounds__(512, 2) void argmin_mfma2(
    const float* __restrict__ X, const f16* __restrict__ W1, const f16* __restrict__ W2,
    const float* __restrict__ sxq, const float* __restrict__ esq,
    int* __restrict__ out_idx) {

    __shared__ char wbuf[65536];   // [sel:2][limb:2][16KB]

    const int tid  = threadIdx.x;
    const int lane = tid & 63;
    const int wv   = tid >> 6;        // 0..7
    const int cl   = lane & 15;       // code-col within 16
    const int q    = lane >> 4;       // 0..3 k-octet
    const int wavetok0 = blockIdx.x * 256 + wv * 32;

    // ---- A: load 32 tokens x 256 dims, split to 2 f16 limbs, keep in regs ----
    // frag (mt, s): lane holds X[wavetok0 + mt*16 + cl][s*32 + q*8 + j], j=0..7
    f16x8 a1[2][8], a2[2][8];
#pragma unroll
    for (int mt = 0; mt < 2; ++mt)
#pragma unroll
        for (int s = 0; s < 8; ++s) {
            const float* p = X + (size_t)(wavetok0 + mt * 16 + cl) * DIM + s * 32 + q * 8;
            float4 v0 = ((const float4*)p)[0];
            float4 v1 = ((const float4*)p)[1];
            float e[8] = {v0.x, v0.y, v0.z, v0.w, v1.x, v1.y, v1.z, v1.w};
#pragma unroll
            for (int j = 0; j < 8; ++j) {
                f16 h = (f16)e[j];
                float r = (e[j] - (float)h) * 2048.0f;   // exact
                a1[mt][s][j] = h;
                a2[mt][s][j] = (f16)r;
            }
        }

    // sx for this lane's 8 token slots: slot = mt*4+r -> token mt*16 + q*4 + r
    float sxr[8];
#pragma unroll
    for (int mt = 0; mt < 2; ++mt)
#pragma unroll
        for (int r = 0; r < 4; ++r)
            sxr[mt * 4 + r] = sxq[wavetok0 + mt * 16 + q * 4 + r];

    float bestd[8];
    int   besti[8];
#pragma unroll
    for (int i = 0; i < 8; ++i) { bestd[i] = 3.4e38f; besti[i] = 0x7fffffff; }

    // ---- staging: 32KB per ct (2 limbs x 32 codes x 512B), 32 wave-instrs, 4/wave.
    // lane i of instr (wv,t): c = 2*cp + (i>>5), o = (i&31) ^ (c&7)
    // -> LDS linear layout seg(c,o) = c*32 + (o ^ (c&7))  (bank-conflict-free reads)
    auto stage = [&](int ct2, int sel) {
#pragma unroll
        for (int t = 0; t < 4; ++t) {
            int fi = wv * 4 + t;
            int L  = fi >> 4;             // limb
            int cp = fi & 15;             // code pair
            int c  = 2 * cp + (lane >> 5);
            int o  = (lane & 31) ^ (c & 7);
            const f16* gsrc = (L ? W2 : W1) + (size_t)(ct2 * 32 + c) * DIM + o * 8;
            char* ldst = wbuf + sel * 32768 + L * 16384 + cp * 1024;
            __builtin_amdgcn_global_load_lds(
                (const __attribute__((address_space(1))) unsigned int*)gsrc,
                (__attribute__((address_space(3))) unsigned int*)ldst, 16, 0, 0);
        }
    };

    stage(0, 0);
    __syncthreads();

    for (int ct = 0; ct < N_CODE / 32; ++ct) {
        if (ct + 1 < N_CODE / 32) stage(ct + 1, (ct + 1) & 1);

        float se0 = esq[ct * 32 + cl];
        float se1 = esq[ct * 32 + 16 + cl];

        f32x4 mainA[2][2], cA[2][2], cB[2][2];
#pragma unroll
        for (int mt = 0; mt < 2; ++mt)
#pragma unroll
            for (int nt = 0; nt < 2; ++nt) {
                mainA[mt][nt] = (f32x4){0.f, 0.f, 0.f, 0.f};
                cA[mt][nt]    = (f32x4){0.f, 0.f, 0.f, 0.f};
                cB[mt][nt]    = (f32x4){0.f, 0.f, 0.f, 0.f};
            }

        const char* base = wbuf + (ct & 1) * 32768;
#pragma unroll
        for (int s = 0; s < 8; ++s) {
            f16x8 b1[2], b2[2];
#pragma unroll
            for (int nt = 0; nt < 2; ++nt) {
                int off = ((nt * 16 + cl) * 32 + (((s * 4 + q) ^ (cl & 7)))) * 16;
                b1[nt] = *(const f16x8*)(base + off);
                b2[nt] = *(const f16x8*)(base + 16384 + off);
            }
#pragma unroll
            for (int mt = 0; mt < 2; ++mt)
#pragma unroll
                for (int nt = 0; nt < 2; ++nt) {
                    mainA[mt][nt] = __builtin_amdgcn_mfma_f32_16x16x32_f16(a1[mt][s], b1[nt], mainA[mt][nt], 0, 0, 0);
                    cA[mt][nt]    = __builtin_amdgcn_mfma_f32_16x16x32_f16(a1[mt][s], b2[nt], cA[mt][nt], 0, 0, 0);
                    cB[mt][nt]    = __builtin_amdgcn_mfma_f32_16x16x32_f16(a2[mt][s], b1[nt], cB[mt][nt], 0, 0, 0);
                }
        }

        // epilogue: d = fl(fl(sx+se) - 2*dot); dot*2^14 = main + 2^-11*(cA+cB)
        // per lane, candidates ascend in code (nt inner, ct outer): strict < keeps lowest.
#pragma unroll
        for (int mt = 0; mt < 2; ++mt)
#pragma unroll
            for (int nt = 0; nt < 2; ++nt)
#pragma unroll
                for (int r = 0; r < 4; ++r) {
                    float cr = cA[mt][nt][r] + cB[mt][nt][r];
                    float mc = fmaf(cr, 4.8828125e-4f, mainA[mt][nt][r]);   // *2^-11
                    float t1 = sxr[mt * 4 + r] + (nt ? se1 : se0);
                    float d  = fmaf(-1.220703125e-4f, mc, t1);              // -2^-13
                    int slot = mt * 4 + r;
                    if (d < bestd[slot]) {
                        bestd[slot] = d;
                        besti[slot] = ct * 32 + nt * 16 + cl;
                    }
                }
        __syncthreads();
    }

    // ---- cross-lane reduction over the 16 code-lanes (lex (d, idx) min) ----
#pragma unroll
    for (int slot = 0; slot < 8; ++slot) {
        float d = bestd[slot];
        int   i = besti[slot];
#pragma unroll
        for (int off = 1; off < 16; off <<= 1) {
            float od = __shfl_xor(d, off, 64);
            int   oi = __shfl_xor(i, off, 64);
            if (od < d || (od == d && oi < i)) { d = od; i = oi; }
        }
        if (cl == 0)
            out_idx[wavetok0 + (slot >> 2) * 16 + q * 4 + (slot & 3)] = i;
    }
}

// ---------- kernel 4: gather + straight-through output + loss partials ----------
__global__ __launch_bounds__(256) void finalize_kernel(
    const float* __restrict__ X, const float* __restrict__ W,
    const int* __restrict__ idx, float* __restrict__ outQ,
    float* __restrict__ outI, double* __restrict__ accum) {
    __shared__ double wsum[4];
    int wid  = threadIdx.x >> 6;
    int lane = threadIdx.x & 63;
    int token = blockIdx.x * 4 + wid;
    int id = idx[token];
    float4 x = ((const float4*)(X + (size_t)token * DIM))[lane];
    float4 qv = ((const float4*)(W + (size_t)id * DIM))[lane];
    float4 o;
    o.x = x.x + (qv.x - x.x);
    o.y = x.y + (qv.y - x.y);
    o.z = x.z + (qv.z - x.z);
    o.w = x.w + (qv.w - x.w);
    ((float4*)(outQ + (size_t)token * DIM))[lane] = o;
    float dx = x.x - qv.x, dy = x.y - qv.y, dz = x.z - qv.z, dw = x.w - qv.w;
    float s = dx * dx + dy * dy + dz * dz + dw * dw;
#pragma unroll
    for (int off = 32; off; off >>= 1) s += __shfl_down(s, off, 64);
    if (lane == 0) {
        outI[token] = (float)id;
        wsum[wid] = (double)s;
    }
    __syncthreads();
    if (threadIdx.x == 0) {
        double t = wsum[0] + wsum[1] + wsum[2] + wsum[3];
        atomicAdd(accum, t);
    }
}

// ---------- kernel 5: scalars ----------
__global__ void scalars_kernel(const double* __restrict__ accum, float* __restrict__ out) {
    double mse = *accum / (double)((size_t)N_TOK * DIM);
    float c = (float)mse;
    out[0] = c + 0.25f * c;
    out[1] = c;
    out[2] = c;
}

extern "C" void kernel_launch(void* const* d_in, const int* in_sizes, int n_in,
                              void* d_out, int out_size, void* d_ws, size_t ws_size,
                              hipStream_t stream) {
    const float* X = (const float*)d_in[0];   // (65536, 256)
    const float* W = (const float*)d_in[1];   // (8192, 256)

    float* outQ = (float*)d_out;
    float* outI = outQ + (size_t)N_TOK * DIM;
    float* outS = outI + N_TOK;

    char* ws = (char*)d_ws;
    double* accum = (double*)ws;                         // @0
    float* esq = (float*)(ws + 64);                      // 32 KB
    float* sxq = (float*)(ws + 64 + 32768);              // 256 KB
    int*   idx = (int*)(ws + 64 + 32768 + 262144);       // 256 KB
    f16*   W1  = (f16*)(ws + (1 << 20));                 // 4 MB
    f16*   W2  = (f16*)(ws + (1 << 20) + 4194304);       // 4 MB

    hipMemsetAsync(accum, 0, sizeof(double), stream);
    splitw_kernel<<<N_CODE * DIM / 4 / 256, 256, 0, stream>>>(W, W1, W2);
    rowsq_kernel<<<N_CODE / 4, 256, 0, stream>>>(W, esq, N_CODE);
    rowsq_kernel<<<N_TOK / 4, 256, 0, stream>>>(X, sxq, N_TOK);
    argmin_mfma2<<<N_TOK / 256, 512, 0, stream>>>(X, W1, W2, sxq, esq, idx);
    finalize_kernel<<<N_TOK / 4, 256, 0, stream>>>(X, W, idx, outQ, outI, accum);
    scalars_kernel<<<1, 1, 0, stream>>>(accum, outS);
}